// Round 1
// baseline (85.813 us; speedup 1.0000x reference)
//
#include <hip/hip_runtime.h>

#define IMG 256
#define TX 64
#define TY 16
#define HALO 3
#define LW (TX + 2 * HALO)   // 70
#define LH (TY + 2 * HALO)   // 22
#define LSTRIDE 72           // pad to keep 16B alignment of float4 rows

__device__ __forceinline__ int reflect_idx(int i) {
    // jnp.pad mode="reflect": -1 -> 1, 256 -> 254
    i = i < 0 ? -i : i;
    i = i > (IMG - 1) ? 2 * (IMG - 1) - i : i;
    return i;
}

__global__ __launch_bounds__(256)
void agf_kernel(const float* __restrict__ x, const float* __restrict__ sigma,
                float* __restrict__ out) {
    __shared__ float tile[LH * LSTRIDE];

    const int plane = blockIdx.z;                 // b*C + c, 0..47
    const int gx0 = blockIdx.x * TX;
    const int gy0 = blockIdx.y * TY;
    const int tid = threadIdx.x;

    const float* xp = x + (size_t)plane * (IMG * IMG);

    // ---- stage x tile (with reflect halo) into LDS ----
    for (int i = tid; i < LH * LW; i += 256) {
        int lr = i / LW;
        int lc = i - lr * LW;
        int gr = reflect_idx(gy0 - HALO + lr);
        int gc = reflect_idx(gx0 - HALO + lc);
        tile[lr * LSTRIDE + lc] = xp[gr * IMG + gc];
    }
    __syncthreads();

    // ---- each thread computes 4 consecutive horizontal pixels ----
    const int tx = tid & 15;       // 0..15
    const int ty = tid >> 4;       // 0..15
    const int col0 = tx * 4;       // local col of first pixel
    const int gy = gy0 + ty;
    const size_t gbase = (size_t)plane * (IMG * IMG) + (size_t)gy * IMG + gx0 + col0;

    const float4 sg = *reinterpret_cast<const float4*>(sigma + gbase);
    const float s[4] = {sg.x, sg.y, sg.z, sg.w};

    float e1[4], e2[4], e3[4], inv[4], acc[4];
    #pragma unroll
    for (int p = 0; p < 4; ++p) {
        const float s2 = s[p] * s[p];
        const float a = __expf(-0.5f * s2);   // e1 = exp(-1/2 * s2)
        const float t = a * a;                // e1^2
        const float b = t * t;                // e1^4 = e2
        const float c = b * b * a;            // e1^9 = e3
        e1[p] = a; e2[p] = b; e3[p] = c;
        const float S = 1.0f + 2.0f * (a + b + c);
        inv[p] = __builtin_amdgcn_rcpf(S * S);  // 1 / (row-sum * col-sum)
        acc[p] = 0.0f;
    }

    #pragma unroll
    for (int r = 0; r < 7; ++r) {
        const float* rowp = &tile[(ty + r) * LSTRIDE + col0];  // 16B aligned
        const float4 v0 = *reinterpret_cast<const float4*>(rowp);
        const float4 v1 = *reinterpret_cast<const float4*>(rowp + 4);
        const float4 v2 = *reinterpret_cast<const float4*>(rowp + 8);
        const float xv[12] = {v0.x, v0.y, v0.z, v0.w,
                              v1.x, v1.y, v1.z, v1.w,
                              v2.x, v2.y, v2.z, v2.w};
        const int dr = (r < 3) ? (3 - r) : (r - 3);
        #pragma unroll
        for (int p = 0; p < 4; ++p) {
            const float rsum = xv[p + 3]
                             + e1[p] * (xv[p + 2] + xv[p + 4])
                             + e2[p] * (xv[p + 1] + xv[p + 5])
                             + e3[p] * (xv[p + 0] + xv[p + 6]);
            if (dr == 0)      acc[p] += rsum;
            else if (dr == 1) acc[p] += e1[p] * rsum;
            else if (dr == 2) acc[p] += e2[p] * rsum;
            else              acc[p] += e3[p] * rsum;
        }
    }

    float4 o;
    o.x = acc[0] * inv[0];
    o.y = acc[1] * inv[1];
    o.z = acc[2] * inv[2];
    o.w = acc[3] * inv[3];
    *reinterpret_cast<float4*>(out + gbase) = o;
}

extern "C" void kernel_launch(void* const* d_in, const int* in_sizes, int n_in,
                              void* d_out, int out_size, void* d_ws, size_t ws_size,
                              hipStream_t stream) {
    const float* x = (const float*)d_in[0];
    const float* sigma = (const float*)d_in[1];
    float* out = (float*)d_out;

    const int planes = in_sizes[0] / (IMG * IMG);   // 16*3 = 48
    dim3 grid(IMG / TX, IMG / TY, planes);          // (4, 16, 48)
    agf_kernel<<<grid, 256, 0, stream>>>(x, sigma, out);
}

// Round 2
// 83.874 us; speedup vs baseline: 1.0231x; 1.0231x over previous
//
#include <hip/hip_runtime.h>

#define IMG 256
#define TX 64
#define TY 16
#define LH 22          // staged rows: gy0-3 .. gy0+18
#define LSTRIDE 72     // staged cols: gx0-4 .. gx0+67 (16B-aligned both ends)
#define NCHUNK (LH * (LSTRIDE / 4))   // 22*18 = 396 float4 chunks

__device__ __forceinline__ int reflect_idx(int i) {
    // jnp.pad mode="reflect": -1 -> 1, 256 -> 254
    i = i < 0 ? -i : i;
    i = i > (IMG - 1) ? 2 * (IMG - 1) - i : i;
    return i;
}

__global__ __launch_bounds__(256)
void agf_kernel(const float* __restrict__ x, const float* __restrict__ sigma,
                float* __restrict__ out) {
    __shared__ float tile[LH * LSTRIDE];

    const int plane = blockIdx.z;                 // b*C + c, 0..47
    const int gx0 = blockIdx.x * TX;
    const int gy0 = blockIdx.y * TY;
    const int tid = threadIdx.x;

    const float* xp = x + (size_t)plane * (IMG * IMG);

    // ---- stage x tile into LDS: float4 chunks, local col lc <-> global gx0-4+lc ----
    #pragma unroll
    for (int it = 0; it < 2; ++it) {
        const int idx = tid + it * 256;
        if (idx < NCHUNK) {
            const int lr = idx / 18;              // chunk row
            const int lc4 = idx - lr * 18;
            const int lcol = lc4 * 4;
            const int grow = reflect_idx(gy0 - 3 + lr);
            const int gcol = gx0 - 4 + lcol;
            const float* src = xp + (size_t)grow * IMG;
            if (gcol >= 0 && gcol <= IMG - 4) {   // aligned vector fast path
                *reinterpret_cast<float4*>(&tile[lr * LSTRIDE + lcol]) =
                    *reinterpret_cast<const float4*>(src + gcol);
            } else {                              // edge chunks: per-element reflect
                #pragma unroll
                for (int j = 0; j < 4; ++j)
                    tile[lr * LSTRIDE + lcol + j] = src[reflect_idx(gcol + j)];
            }
        }
    }
    __syncthreads();

    // ---- each thread computes 4 consecutive horizontal pixels ----
    const int tx = tid & 15;       // 0..15
    const int ty = tid >> 4;       // 0..15
    const int col0 = tx * 4;       // pixel p: global col gx0+col0+p, local col0+p+4
    const int gy = gy0 + ty;
    const size_t gbase = (size_t)plane * (IMG * IMG) + (size_t)gy * IMG + gx0 + col0;

    const float4 sg = *reinterpret_cast<const float4*>(sigma + gbase);
    const float s[4] = {sg.x, sg.y, sg.z, sg.w};

    float e1[4], e2[4], e3[4], inv[4], acc[4];
    #pragma unroll
    for (int p = 0; p < 4; ++p) {
        const float s2 = s[p] * s[p];
        const float a = __expf(-0.5f * s2);   // e1
        const float t = a * a;
        const float b = t * t;                // e1^4 = e2
        const float c = b * b * a;            // e1^9 = e3
        e1[p] = a; e2[p] = b; e3[p] = c;
        const float S = 1.0f + 2.0f * (a + b + c);
        inv[p] = __builtin_amdgcn_rcpf(S * S);
        acc[p] = 0.0f;
    }

    // helper lambda: horizontal weighted sum over a 12-float row segment
    // pixel p needs segment indices p+1 .. p+7 (center p+4)
    auto rsum = [&](const float v[12], int p) {
        return v[p + 4]
             + e1[p] * (v[p + 3] + v[p + 5])
             + e2[p] * (v[p + 2] + v[p + 6])
             + e3[p] * (v[p + 1] + v[p + 7]);
    };

    // row pairs dr = +/-(3-q) share the multiplier e_{3-q}; rsum is linear,
    // so add the two rows first, then one rsum + one fma per pixel.
    #pragma unroll
    for (int q = 0; q < 3; ++q) {
        const float* rowA = &tile[(ty + q) * LSTRIDE + col0];        // 16B aligned
        const float* rowB = &tile[(ty + 6 - q) * LSTRIDE + col0];
        const float4 a0 = *reinterpret_cast<const float4*>(rowA);
        const float4 a1 = *reinterpret_cast<const float4*>(rowA + 4);
        const float4 a2 = *reinterpret_cast<const float4*>(rowA + 8);
        const float4 b0 = *reinterpret_cast<const float4*>(rowB);
        const float4 b1 = *reinterpret_cast<const float4*>(rowB + 4);
        const float4 b2 = *reinterpret_cast<const float4*>(rowB + 8);
        const float vs[12] = {a0.x + b0.x, a0.y + b0.y, a0.z + b0.z, a0.w + b0.w,
                              a1.x + b1.x, a1.y + b1.y, a1.z + b1.z, a1.w + b1.w,
                              a2.x + b2.x, a2.y + b2.y, a2.z + b2.z, a2.w + b2.w};
        #pragma unroll
        for (int p = 0; p < 4; ++p) {
            const float er = (q == 0) ? e3[p] : (q == 1) ? e2[p] : e1[p];
            acc[p] += er * rsum(vs, p);
        }
    }
    {   // center row (dr = 0, multiplier 1)
        const float* rowC = &tile[(ty + 3) * LSTRIDE + col0];
        const float4 c0 = *reinterpret_cast<const float4*>(rowC);
        const float4 c1 = *reinterpret_cast<const float4*>(rowC + 4);
        const float4 c2 = *reinterpret_cast<const float4*>(rowC + 8);
        const float vc[12] = {c0.x, c0.y, c0.z, c0.w,
                              c1.x, c1.y, c1.z, c1.w,
                              c2.x, c2.y, c2.z, c2.w};
        #pragma unroll
        for (int p = 0; p < 4; ++p)
            acc[p] += rsum(vc, p);
    }

    float4 o;
    o.x = acc[0] * inv[0];
    o.y = acc[1] * inv[1];
    o.z = acc[2] * inv[2];
    o.w = acc[3] * inv[3];
    *reinterpret_cast<float4*>(out + gbase) = o;
}

extern "C" void kernel_launch(void* const* d_in, const int* in_sizes, int n_in,
                              void* d_out, int out_size, void* d_ws, size_t ws_size,
                              hipStream_t stream) {
    const float* x = (const float*)d_in[0];
    const float* sigma = (const float*)d_in[1];
    float* out = (float*)d_out;

    const int planes = in_sizes[0] / (IMG * IMG);   // 16*3 = 48
    dim3 grid(IMG / TX, IMG / TY, planes);          // (4, 16, 48)
    agf_kernel<<<grid, 256, 0, stream>>>(x, sigma, out);
}